// Round 27
// baseline (1778.121 us; speedup 1.0000x reference)
//
#include <hip/hip_runtime.h>
#include <math.h>

typedef _Float16 h16;
typedef __attribute__((ext_vector_type(8))) _Float16 half8;
typedef __attribute__((ext_vector_type(4))) _Float16 half4;
typedef __attribute__((ext_vector_type(4))) float f32x4;

#define DEVI static __device__ __forceinline__

constexpr int LAY = 8, E = 1024, NH = 16, T = 1024, VOC = 32000, BATCH = 2, HD = 64;
constexpr int MROWS = BATCH * T; // 2048
constexpr int E2 = E * E;

DEVI void glds16(const void* g, void* l) {
  __builtin_amdgcn_global_load_lds((const __attribute__((address_space(1))) void*)g,
                                   (__attribute__((address_space(3))) void*)l, 16, 0, 0);
}

// ---------------- weight-encoding detector (parallel) ----------------
__global__ __launch_bounds__(256) void prep_stride_k(const unsigned char* __restrict__ qw1,
                                                     const unsigned char* __restrict__ qw2,
                                                     int* __restrict__ stridew) {
  __shared__ int red2[4], red4[4];
  const int tid = threadIdx.x;
  const int NB = 8192;
  int c2 = 0, c4 = 0;
  for (int i = tid; i < NB; i += 256) {
    const unsigned char b1 = qw1[i], b2 = qw2[i];
    const int s1 = (b1 == 0x00 || b1 == 0xFF) ? 1 : 0;
    const int s2 = (b2 == 0x00 || b2 == 0xFF) ? 1 : 0;
    if (i & 1) c2 += s1 + s2;
    if (i & 3) c4 += s1 + s2;
  }
#pragma unroll
  for (int d = 32; d >= 1; d >>= 1) { c2 += __shfl_xor(c2, d); c4 += __shfl_xor(c4, d); }
  if ((tid & 63) == 0) { red2[tid >> 6] = c2; red4[tid >> 6] = c4; }
  __syncthreads();
  if (tid == 0) {
    const int t2 = red2[0] + red2[1] + red2[2] + red2[3];
    const int t4 = red4[0] + red4[1] + red4[2] + red4[3];
    int stride = 1;
    if (t4 > (NB * 3 / 2) * 98 / 100) stride = 4;
    else if (t2 > NB * 98 / 100) stride = 2;
    stridew[0] = stride;
  }
}

// ---------------- widened int8 -> 8x f16 loader ----------------
DEVI half8 dq8(const signed char* src, int bstr, float s) {
  half8 o;
  if (bstr == 4) {
    int4 r0 = *reinterpret_cast<const int4*>(src);
    int4 r1 = *reinterpret_cast<const int4*>(src + 16);
    const int* c0 = reinterpret_cast<const int*>(&r0);
    const int* c1 = reinterpret_cast<const int*>(&r1);
#pragma unroll
    for (int j = 0; j < 4; ++j) o[j] = (h16)((float)c0[j] * s);
#pragma unroll
    for (int j = 0; j < 4; ++j) o[4 + j] = (h16)((float)c1[j] * s);
  } else if (bstr == 2) {
    int4 r0 = *reinterpret_cast<const int4*>(src);
    const short* c0 = reinterpret_cast<const short*>(&r0);
#pragma unroll
    for (int j = 0; j < 8; ++j) o[j] = (h16)((float)c0[j] * s);
  } else {
    int2 r0 = *reinterpret_cast<const int2*>(src);
    const signed char* c0 = reinterpret_cast<const signed char*>(&r0);
#pragma unroll
    for (int j = 0; j < 8; ++j) o[j] = (h16)((float)c0[j] * s);
  }
  return o;
}

// ---------------- bulk dequant (single scale region, used for LM) ----------------
__global__ __launch_bounds__(256) void dequant_all_k(const signed char* __restrict__ q,
                                                     const int* __restrict__ strideptr,
                                                     const float* __restrict__ sp, int P,
                                                     h16* __restrict__ out, int n) {
  const int i = (blockIdx.x * 256 + threadIdx.x) * 8;
  if (i >= n) return;
  const float s = sp[i / P];
  const int bstr = strideptr[0];
  *reinterpret_cast<half8*>(out + i) = dq8(q + (size_t)i * (size_t)bstr, bstr, s);
}

// ---------------- merged per-layer dequant: qkv | aproj | fc | mproj ----------------
__global__ __launch_bounds__(256) void dequant_layer_k(
    const signed char* __restrict__ qkv_q, const signed char* __restrict__ ap_q,
    const signed char* __restrict__ fc_q, const signed char* __restrict__ mp_q,
    const float* __restrict__ qkv_s, const float* __restrict__ ap_s,
    const float* __restrict__ fc_s, const float* __restrict__ mp_s, int l,
    const int* __restrict__ strideptr,
    h16* __restrict__ wq, h16* __restrict__ wa, h16* __restrict__ wf,
    h16* __restrict__ wm) {
  const int e = (blockIdx.x * 256 + threadIdx.x) * 8;
  const int bstr = strideptr[0];
  const signed char* src;
  h16* dst;
  float s;
  if (e < 3 * E2) {
    src = qkv_q + ((size_t)l * 3 * E2 + e) * (size_t)bstr;
    dst = wq + e;
    s = qkv_s[l];
  } else if (e < 4 * E2) {
    const int e2 = e - 3 * E2;
    src = ap_q + ((size_t)l * E2 + e2) * (size_t)bstr;
    dst = wa + e2;
    s = ap_s[l];
  } else if (e < 8 * E2) {
    const int e2 = e - 4 * E2;
    src = fc_q + ((size_t)l * 4 * E2 + e2) * (size_t)bstr;
    dst = wf + e2;
    s = fc_s[l];
  } else {
    const int e2 = e - 8 * E2;
    src = mp_q + ((size_t)l * 4 * E2 + e2) * (size_t)bstr;
    dst = wm + e2;
    s = mp_s[l];
  }
  *reinterpret_cast<half8*>(dst) = dq8(src, bstr, s);
}

// ---------------- embedding ----------------
__global__ __launch_bounds__(256) void embed_k(const int* __restrict__ idx,
                                               const float* __restrict__ tok,
                                               const float* __restrict__ pos,
                                               float* __restrict__ x) {
  const int row = blockIdx.x;
  const int t = row & (T - 1);
  const int id = idx[row];
  const float4 a = reinterpret_cast<const float4*>(tok + (size_t)id * E)[threadIdx.x];
  const float4 p = reinterpret_cast<const float4*>(pos + (size_t)t * E)[threadIdx.x];
  float4 o; o.x = a.x + p.x; o.y = a.y + p.y; o.z = a.z + p.z; o.w = a.w + p.w;
  reinterpret_cast<float4*>(x + (size_t)row * E)[threadIdx.x] = o;
}

// ---------------- layernorm (f32 in -> f16 out) ----------------
__global__ __launch_bounds__(256) void ln_k(const float* __restrict__ x,
                                            const float* __restrict__ g,
                                            const float* __restrict__ bb,
                                            h16* __restrict__ out) {
  __shared__ float red[8];
  const int row = blockIdx.x, tid = threadIdx.x;
  const float4 v = reinterpret_cast<const float4*>(x + (size_t)row * E)[tid];
  float s1 = v.x + v.y + v.z + v.w;
  float s2 = v.x * v.x + v.y * v.y + v.z * v.z + v.w * v.w;
#pragma unroll
  for (int d = 32; d >= 1; d >>= 1) { s1 += __shfl_xor(s1, d); s2 += __shfl_xor(s2, d); }
  if ((tid & 63) == 0) { red[tid >> 6] = s1; red[4 + (tid >> 6)] = s2; }
  __syncthreads();
  s1 = red[0] + red[1] + red[2] + red[3];
  s2 = red[4] + red[5] + red[6] + red[7];
  const float mean = s1 * (1.0f / E);
  const float var = s2 * (1.0f / E) - mean * mean;
  const float rstd = rsqrtf(var + 1e-5f);
  const float4 gv = reinterpret_cast<const float4*>(g)[tid];
  const float4 bv = reinterpret_cast<const float4*>(bb)[tid];
  half4 o;
  o[0] = (h16)((v.x - mean) * rstd * gv.x + bv.x);
  o[1] = (h16)((v.y - mean) * rstd * gv.y + bv.y);
  o[2] = (h16)((v.z - mean) * rstd * gv.z + bv.z);
  o[3] = (h16)((v.w - mean) * rstd * gv.w + bv.w);
  *reinterpret_cast<half4*>(out + (size_t)row * E + tid * 4) = o;
}

// ---------------- fused split-K reduce + residual + LN ----------------
__global__ __launch_bounds__(256) void reduce_ln_k(const float* __restrict__ pbuf, int S,
                                                   const float* __restrict__ bias,
                                                   float* __restrict__ x,
                                                   const float* __restrict__ g,
                                                   const float* __restrict__ bb,
                                                   h16* __restrict__ out) {
  __shared__ float red[8];
  const int row = blockIdx.x, tid = threadIdx.x;
  const size_t base = (size_t)row * E + tid * 4;
  float4 a = *reinterpret_cast<const float4*>(pbuf + base);
  for (int s = 1; s < S; ++s) {
    const float4 p = *reinterpret_cast<const float4*>(pbuf + (size_t)s * MROWS * E + base);
    a.x += p.x; a.y += p.y; a.z += p.z; a.w += p.w;
  }
  const float4 bv0 = *reinterpret_cast<const float4*>(bias + tid * 4);
  float4 v = *reinterpret_cast<const float4*>(x + base);
  v.x += a.x + bv0.x; v.y += a.y + bv0.y; v.z += a.z + bv0.z; v.w += a.w + bv0.w;
  *reinterpret_cast<float4*>(x + base) = v;
  float s1 = v.x + v.y + v.z + v.w;
  float s2 = v.x * v.x + v.y * v.y + v.z * v.z + v.w * v.w;
#pragma unroll
  for (int d = 32; d >= 1; d >>= 1) { s1 += __shfl_xor(s1, d); s2 += __shfl_xor(s2, d); }
  if ((tid & 63) == 0) { red[tid >> 6] = s1; red[4 + (tid >> 6)] = s2; }
  __syncthreads();
  s1 = red[0] + red[1] + red[2] + red[3];
  s2 = red[4] + red[5] + red[6] + red[7];
  const float mean = s1 * (1.0f / E);
  const float var = s2 * (1.0f / E) - mean * mean;
  const float rstd = rsqrtf(var + 1e-5f);
  const float4 gv = *reinterpret_cast<const float4*>(g + tid * 4);
  const float4 lb = *reinterpret_cast<const float4*>(bb + tid * 4);
  half4 o;
  o[0] = (h16)((v.x - mean) * rstd * gv.x + lb.x);
  o[1] = (h16)((v.y - mean) * rstd * gv.y + lb.y);
  o[2] = (h16)((v.z - mean) * rstd * gv.z + lb.z);
  o[3] = (h16)((v.w - mean) * rstd * gv.w + lb.w);
  *reinterpret_cast<half4*>(out + (size_t)row * E + tid * 4) = o;
}

// swizzle helper (kept; bit-identical fragment contents, rule #21 both-sides form)
DEVI int swz4(int r) { return (r ^ (r >> 2)) & 3; }

// ---------------- 256x128-tile 8-wave GEMM: phase-split, counted vmcnt ----------------
// Waves 4m x 2n, wave tile 64x64. Per K-tile (BK=32):
//   P1 {read af[0..1]+bfr[0..3]; stage A(t+1) [2 calls]; lgkm0; 8 MFMA}, barrier;
//   P2 {read af[2..3]; stage B(t+2) [1 call]; vmcnt(1); lgkm0; 8 MFMA}, barrier.
// vmcnt(1) at P2(t): outstanding {B(t+1), A(t+1)x2, B(t+2)} -> retires oldest 3
// => tile t+1 fully landed. Slot safety identical to the proven LM template.
// OUT_KIND: 0 = f32, 1 = f16
template <int OUT_KIND, int DO_GELU, int DO_RESID>
__global__ __launch_bounds__(512) void gemm_bt(const h16* __restrict__ A,
                                               const h16* __restrict__ Bw,
                                               const float* __restrict__ bias,
                                               const float* __restrict__ resid,
                                               void* __restrict__ Cout,
                                               int M, int N, int K, int ldc) {
  __shared__ __align__(16) h16 As[2][8192];  // [256][32]
  __shared__ __align__(16) h16 Bs[2][4096];  // [128][32]
  const int tid = threadIdx.x;
  const int w = tid >> 6, lane = tid & 63;
  const int lin = blockIdx.x;
  const int cpx = gridDim.x >> 3;
  const int swz = (lin & 7) * cpx + (lin >> 3);
  const int m0 = (swz & 7) << 8;    // 8 m-tiles of 256 (M = 2048)
  const int n0 = (swz >> 3) << 7;   // n-tiles of 128
  const int wr = w >> 1, wc = w & 1;  // 4m x 2n waves, wave tile 64x64
  const int lr = lane >> 2;
  const int lc8 = (((lane & 3) ^ swz4(lr)) << 3);
  const h16* gA = A + (size_t)(m0 + w * 16 + lr) * K + lc8;
  const h16* gB = Bw + (size_t)(n0 + w * 16 + lr) * K + lc8;
  f32x4 acc[4][4] = {};
  const int fl = lane & 15;
  const int fkx = (((lane >> 4) ^ swz4(fl)) << 3);
  const int nk = K >> 5;
  auto stageA = [&](int buf, int kt, int half) {
    glds16(gA + (size_t)(kt << 5) + (size_t)half * 128 * K,
           &As[buf][half * 4096 + w * 512]);
  };
  auto stageB = [&](int buf, int kt) {
    glds16(gB + (size_t)(kt << 5), &Bs[buf][w * 512]);
  };
  stageA(0, 0, 0); stageA(0, 0, 1);
  stageB(0, 0);
  stageB(1, 1);
  asm volatile("s_waitcnt vmcnt(1)" ::: "memory");
  asm volatile("s_barrier" ::: "memory");
  int cur = 0;
  for (int kt = 0; kt < nk; ++kt) {
    half8 af[4], bfr[4];
    // ---- phase 1: mi 0..1 ----
#pragma unroll
    for (int mi = 0; mi < 2; ++mi)
      af[mi] = *reinterpret_cast<const half8*>(&As[cur][(wr * 64 + mi * 16 + fl) * 32 + fkx]);
#pragma unroll
    for (int ni = 0; ni < 4; ++ni)
      bfr[ni] = *reinterpret_cast<const half8*>(&Bs[cur][(wc * 64 + ni * 16 + fl) * 32 + fkx]);
    if (kt + 1 < nk) { stageA(cur ^ 1, kt + 1, 0); stageA(cur ^ 1, kt + 1, 1); }
    asm volatile("s_waitcnt lgkmcnt(0)" ::: "memory");
    __builtin_amdgcn_sched_barrier(0);
    __builtin_amdgcn_s_setprio(1);
#pragma unroll
    for (int mi = 0; mi < 2; ++mi)
#pragma unroll
      for (int ni = 0; ni < 4; ++ni)
        acc[mi][ni] = __builtin_amdgcn_mfma_f32_16x16x32_f16(af[mi], bfr[ni], acc[mi][ni], 0, 0, 0);
    __builtin_amdgcn_s_setprio(0);
    asm volatile("s_barrier" ::: "memory");
    // ---- phase 2: mi 2..3 ----
#pragma unroll
    for (int mi = 2; mi < 4; ++mi)
      af[mi] = *reinterpret_cast<const half8*>(&As[cur][(wr * 64 + mi * 16 + fl) * 32 + fkx]);
    if (kt + 2 < nk) stageB(cur, kt + 2);
    if (kt < nk - 2)
      asm volatile("s_waitcnt vmcnt(1)" ::: "memory");
    else
      asm volatile("s_waitcnt vmcnt(0)" ::: "memory");
    asm volatile("s_waitcnt lgkmcnt(0)" ::: "memory");
    __builtin_amdgcn_sched_barrier(0);
    __builtin_amdgcn_s_setprio(1);
#pragma unroll
    for (int mi = 2; mi < 4; ++mi)
#pragma unroll
      for (int ni = 0; ni < 4; ++ni)
        acc[mi][ni] = __builtin_amdgcn_mfma_f32_16x16x32_f16(af[mi], bfr[ni], acc[mi][ni], 0, 0, 0);
    __builtin_amdgcn_s_setprio(0);
    asm volatile("s_barrier" ::: "memory");
    cur ^= 1;
  }
  const int fr4 = (lane >> 4) << 2;
#pragma unroll
  for (int mi = 0; mi < 4; ++mi) {
#pragma unroll
    for (int ni = 0; ni < 4; ++ni) {
      const int col = n0 + wc * 64 + ni * 16 + fl;
      const float bv = bias ? bias[col] : 0.0f;
#pragma unroll
      for (int j = 0; j < 4; ++j) {
        const int row = m0 + wr * 64 + mi * 16 + fr4 + j;
        float v = acc[mi][ni][j] + bv;
        if (DO_GELU) v = 0.5f * v * (1.0f + erff(v * 0.70710678118f));
        if (DO_RESID) v += resid[(size_t)row * ldc + col];
        if (OUT_KIND == 1)
          reinterpret_cast<h16*>(Cout)[(size_t)row * ldc + col] = (h16)v;
        else
          reinterpret_cast<float*>(Cout)[(size_t)row * ldc + col] = v;
      }
    }
  }
}

// ---------------- 256x256 8-wave LM GEMM: phase-split, counted vmcnt (proven) ---------
__global__ __launch_bounds__(512) void gemm_bt256(const h16* __restrict__ A,
                                                  const h16* __restrict__ Bw,
                                                  float* __restrict__ Cout,
                                                  int M, int N, int K) {
  __shared__ __align__(16) h16 As[2][8192];
  __shared__ __align__(16) h16 Bs[2][8192];
  const int tid = threadIdx.x;
  const int w = tid >> 6, lane = tid & 63;
  const int lin = blockIdx.x;
  const int cpx = gridDim.x >> 3;
  const int swz = (lin & 7) * cpx + (lin >> 3);
  const int m0 = (swz & 7) << 8;
  const int n0 = (swz >> 3) << 8;
  const int wr = w >> 2, wc = w & 3;  // 2m x 4n waves, wave tile 128x64
  const int lr = lane >> 2;
  const int lc8 = (((lane & 3) ^ swz4(lr)) << 3);
  const h16* gA = A + (size_t)(m0 + w * 16 + lr) * K + lc8;
  const h16* gB = Bw + (size_t)(n0 + w * 16 + lr) * K + lc8;
  f32x4 acc[8][4] = {};
  const int fl = lane & 15;
  const int fkx = (((lane >> 4) ^ swz4(fl)) << 3);
  const int nk = K >> 5;  // 32
  auto stageA = [&](int buf, int kt, int half) {
    glds16(gA + (size_t)(kt << 5) + (size_t)half * 128 * K,
           &As[buf][half * 4096 + w * 512]);
  };
  auto stageB = [&](int buf, int kt, int half) {
    glds16(gB + (size_t)(kt << 5) + (size_t)half * 128 * K,
           &Bs[buf][half * 4096 + w * 512]);
  };
  stageA(0, 0, 0); stageA(0, 0, 1);
  stageB(0, 0, 0); stageB(0, 0, 1);
  stageB(1, 1, 0); stageB(1, 1, 1);
  asm volatile("s_waitcnt vmcnt(2)" ::: "memory");
  asm volatile("s_barrier" ::: "memory");
  int cur = 0;
  for (int kt = 0; kt < nk; ++kt) {
    half8 af[4], bfr[4];
    // ---- phase 1: mlo x n ----
#pragma unroll
    for (int mi = 0; mi < 4; ++mi)
      af[mi] = *reinterpret_cast<const half8*>(&As[cur][(wr * 128 + mi * 16 + fl) * 32 + fkx]);
#pragma unroll
    for (int ni = 0; ni < 4; ++ni)
      bfr[ni] = *reinterpret_cast<const half8*>(&Bs[cur][(wc * 64 + ni * 16 + fl) * 32 + fkx]);
    if (kt + 1 < nk) { stageA(cur ^ 1, kt + 1, 0); stageA(cur ^ 1, kt + 1, 1); }
    asm volatile("s_waitcnt lgkmcnt(0)" ::: "memory");
    __builtin_amdgcn_sched_barrier(0);
    __builtin_amdgcn_s_setprio(1);
#pragma unroll
    for (int mi = 0; mi < 4; ++mi)
#pragma unroll
      for (int ni = 0; ni < 4; ++ni)
        acc[mi][ni] = __builtin_amdgcn_mfma_f32_16x16x32_f16(af[mi], bfr[ni], acc[mi][ni], 0, 0, 0);
    __builtin_amdgcn_s_setprio(0);
    asm volatile("s_barrier" ::: "memory");
    // ---- phase 2: mhi x n ----
#pragma unroll
    for (int mi = 0; mi < 4; ++mi)
      af[mi] = *reinterpret_cast<const half8*>(
          &As[cur][(wr * 128 + 64 + mi * 16 + fl) * 32 + fkx]);
    if (kt + 2 < nk) { stageB(cur, kt + 2, 0); stageB(cur, kt + 2, 1); }
    if (kt < nk - 2)
      asm volatile("s_waitcnt vmcnt(2)" ::: "memory");
    else
      asm volatile("s_waitcnt vmcnt(0)" ::: "memory");
    asm volatile("s_waitcnt lgkmcnt(0)" ::: "memory");
    __builtin_amdgcn_sched_barrier(0);
    __builtin_amdgcn_s_setprio(1);
#pragma unroll
    for (int mi = 0; mi < 4; ++mi)
#pragma unroll
      for (int ni = 0; ni < 4; ++ni)
        acc[4 + mi][ni] =
            __builtin_amdgcn_mfma_f32_16x16x32_f16(af[mi], bfr[ni], acc[4 + mi][ni], 0, 0, 0);
    __builtin_amdgcn_s_setprio(0);
    asm volatile("s_barrier" ::: "memory");
    cur ^= 1;
  }
  const int fr4 = (lane >> 4) << 2;
#pragma unroll
  for (int mi = 0; mi < 8; ++mi)
#pragma unroll
    for (int ni = 0; ni < 4; ++ni) {
      const int col = n0 + wc * 64 + ni * 16 + fl;
#pragma unroll
      for (int j = 0; j < 4; ++j) {
        const int row = m0 + wr * 128 + mi * 16 + fr4 + j;
        Cout[(size_t)row * N + col] = acc[mi][ni][j];
      }
    }
}

// ---------------- split-K GEMM (256x128 8-wave, phase-split, counted vmcnt) ----------
__global__ __launch_bounds__(512) void gemm_btk(const h16* __restrict__ A,
                                                const h16* __restrict__ Bw,
                                                float* __restrict__ pbuf,
                                                int M, int N, int Kc, int ldk) {
  __shared__ __align__(16) h16 As[2][8192];
  __shared__ __align__(16) h16 Bs[2][4096];
  const int tid = threadIdx.x;
  const int w = tid >> 6, lane = tid & 63;
  const int lin = blockIdx.x;
  const int cpx = gridDim.x >> 3;
  const int swz = (lin & 7) * cpx + (lin >> 3);
  const int m0 = (swz & 7) << 8;
  const int n0 = (swz >> 3) << 7;
  const int s = blockIdx.y;
  const int koff = s * Kc;
  const int wr = w >> 1, wc = w & 1;
  const int lr = lane >> 2;
  const int lc8 = (((lane & 3) ^ swz4(lr)) << 3);
  const h16* gA = A + (size_t)(m0 + w * 16 + lr) * ldk + koff + lc8;
  const h16* gB = Bw + (size_t)(n0 + w * 16 + lr) * ldk + koff + lc8;
  f32x4 acc[4][4] = {};
  const int fl = lane & 15;
  const int fkx = (((lane >> 4) ^ swz4(fl)) << 3);
  const int nk = Kc >> 5;
  auto stageA = [&](int buf, int kt, int half) {
    glds16(gA + (size_t)(kt << 5) + (size_t)half * 128 * ldk,
           &As[buf][half * 4096 + w * 512]);
  };
  auto stageB = [&](int buf, int kt) {
    glds16(gB + (size_t)(kt << 5), &Bs[buf][w * 512]);
  };
  stageA(0, 0, 0); stageA(0, 0, 1);
  stageB(0, 0);
  stageB(1, 1);
  asm volatile("s_waitcnt vmcnt(1)" ::: "memory");
  asm volatile("s_barrier" ::: "memory");
  int cur = 0;
  for (int kt = 0; kt < nk; ++kt) {
    half8 af[4], bfr[4];
#pragma unroll
    for (int mi = 0; mi < 2; ++mi)
      af[mi] = *reinterpret_cast<const half8*>(&As[cur][(wr * 64 + mi * 16 + fl) * 32 + fkx]);
#pragma unroll
    for (int ni = 0; ni < 4; ++ni)
      bfr[ni] = *reinterpret_cast<const half8*>(&Bs[cur][(wc * 64 + ni * 16 + fl) * 32 + fkx]);
    if (kt + 1 < nk) { stageA(cur ^ 1, kt + 1, 0); stageA(cur ^ 1, kt + 1, 1); }
    asm volatile("s_waitcnt lgkmcnt(0)" ::: "memory");
    __builtin_amdgcn_sched_barrier(0);
    __builtin_amdgcn_s_setprio(1);
#pragma unroll
    for (int mi = 0; mi < 2; ++mi)
#pragma unroll
      for (int ni = 0; ni < 4; ++ni)
        acc[mi][ni] = __builtin_amdgcn_mfma_f32_16x16x32_f16(af[mi], bfr[ni], acc[mi][ni], 0, 0, 0);
    __builtin_amdgcn_s_setprio(0);
    asm volatile("s_barrier" ::: "memory");
#pragma unroll
    for (int mi = 2; mi < 4; ++mi)
      af[mi] = *reinterpret_cast<const half8*>(&As[cur][(wr * 64 + mi * 16 + fl) * 32 + fkx]);
    if (kt + 2 < nk) stageB(cur, kt + 2);
    if (kt < nk - 2)
      asm volatile("s_waitcnt vmcnt(1)" ::: "memory");
    else
      asm volatile("s_waitcnt vmcnt(0)" ::: "memory");
    asm volatile("s_waitcnt lgkmcnt(0)" ::: "memory");
    __builtin_amdgcn_sched_barrier(0);
    __builtin_amdgcn_s_setprio(1);
#pragma unroll
    for (int mi = 2; mi < 4; ++mi)
#pragma unroll
      for (int ni = 0; ni < 4; ++ni)
        acc[mi][ni] = __builtin_amdgcn_mfma_f32_16x16x32_f16(af[mi], bfr[ni], acc[mi][ni], 0, 0, 0);
    __builtin_amdgcn_s_setprio(0);
    asm volatile("s_barrier" ::: "memory");
    cur ^= 1;
  }
  float* out = pbuf + (size_t)s * M * N;
  const int fr4 = (lane >> 4) << 2;
#pragma unroll
  for (int mi = 0; mi < 4; ++mi)
#pragma unroll
    for (int ni = 0; ni < 4; ++ni) {
      const int col = n0 + wc * 64 + ni * 16 + fl;
#pragma unroll
      for (int j = 0; j < 4; ++j) {
        const int row = m0 + wr * 64 + mi * 16 + fr4 + j;
        out[(size_t)row * N + col] = acc[mi][ni][j];
      }
    }
}

// ---------------- MFMA causal flash attention (dbuf K/V + reversed qt) ----------------
__global__ __launch_bounds__(256) void attn_k(const h16* __restrict__ qkv,
                                              h16* __restrict__ yout) {
  __shared__ __align__(16) h16 Ks[2][4096];
  __shared__ __align__(16) h16 VTs[2][4096];
  __shared__ __align__(16) h16 Ps[4096];
  const int qt = (int)gridDim.x - 1 - (int)blockIdx.x;
  const int bh = blockIdx.y;
  const int b = bh >> 4, h = bh & 15;
  const int tid = threadIdx.x, w = tid >> 6, lane = tid & 63;
  const int fl = lane & 15, fkg = lane >> 4, fk = fkg << 3;
  const size_t rowQ0 = (size_t)b * T + qt * 64 + w * 16;
  const h16* qbase = qkv + (rowQ0 + fl) * 3072 + h * 64;
  const half8 qf0 = *reinterpret_cast<const half8*>(qbase + fk);
  const half8 qf1 = *reinterpret_cast<const half8*>(qbase + 32 + fk);
  f32x4 yacc[4] = {};
  float m_run[4], l_run[4];
#pragma unroll
  for (int j = 0; j < 4; ++j) { m_run[j] = -1e30f; l_run[j] = 0.f; }
  const int q_g0 = qt * 64 + w * 16 + (fkg << 2);
  const int krow = lane >> 3, kcol8 = (lane & 7) << 3;
  const int vrow = tid >> 2, vcol8 = (tid & 3) << 3;

  auto stageK = [&](int kt, int buf) {
    const size_t kbase = (size_t)b * T + kt * 64;
    const h16* gk = qkv + (kbase + w * 8 + krow) * 3072 + E + h * 64 + kcol8;
    glds16(gk, &Ks[buf][w * 512]);
    glds16(gk + (size_t)32 * 3072, &Ks[buf][2048 + w * 512]);
  };
  auto loadV = [&](int kt, int half32) {
    const size_t kbase = (size_t)b * T + kt * 64;
    return *reinterpret_cast<const half8*>(qkv + (kbase + vrow) * 3072 + 2 * E + h * 64 +
                                           vcol8 + half32);
  };
  auto scatterV = [&](int buf, half8 v0, half8 v1) {
#pragma unroll
    for (int e = 0; e < 8; ++e) VTs[buf][(vcol8 + e) * 64 + vrow] = v0[e];
#pragma unroll
    for (int e = 0; e < 8; ++e) VTs[buf][(vcol8 + 32 + e) * 64 + vrow] = v1[e];
  };

  stageK(0, 0);
  {
    half8 v0 = loadV(0, 0), v1 = loadV(0, 32);
    scatterV(0, v0, v1);
  }
  __syncthreads();
  int cur = 0;
  for (int kt = 0; kt <= qt; ++kt) {
    const bool hn = kt < qt;
    half8 nv0, nv1;
    if (hn) {
      stageK(kt + 1, cur ^ 1);
      nv0 = loadV(kt + 1, 0);
      nv1 = loadV(kt + 1, 32);
    }
    f32x4 sacc[4];
#pragma unroll
    for (int ni = 0; ni < 4; ++ni) {
      const half8 kb0 = *reinterpret_cast<const half8*>(&Ks[cur][(ni * 16 + fl) * 64 + fk]);
      const half8 kb1 = *reinterpret_cast<const half8*>(&Ks[cur][(ni * 16 + fl) * 64 + 32 + fk]);
      f32x4 z = {0.f, 0.f, 0.f, 0.f};
      z = __builtin_amdgcn_mfma_f32_16x16x32_f16(qf0, kb0, z, 0, 0, 0);
      z = __builtin_amdgcn_mfma_f32_16x16x32_f16(qf1, kb1, z, 0, 0, 0);
      sacc[ni] = z;
    }
    float tmax[4] = {-1e30f, -1e30f, -1e30f, -1e30f};
#pragma unroll
    for (int ni = 0; ni < 4; ++ni) {
      const int kcol = kt * 64 + ni * 16 + fl;
#pragma unroll
      for (int j = 0; j < 4; ++j) {
        float sv = sacc[ni][j] * 0.125f;
        sv = (kcol > q_g0 + j) ? -1e30f : sv;
        sacc[ni][j] = sv;
        tmax[j] = fmaxf(tmax[j], sv);
      }
    }
#pragma unroll
    for (int d = 1; d < 16; d <<= 1) {
#pragma unroll
      for (int j = 0; j < 4; ++j) tmax[j] = fmaxf(tmax[j], __shfl_xor(tmax[j], d));
    }
    float sc_old[4], psum[4] = {0.f, 0.f, 0.f, 0.f};
#pragma unroll
    for (int j = 0; j < 4; ++j) {
      const float mn = fmaxf(m_run[j], tmax[j]);
      sc_old[j] = __expf(m_run[j] - mn);
      m_run[j] = mn;
    }
#pragma unroll
    for (int ni = 0; ni < 4; ++ni)
#pragma unroll
      for (int j = 0; j < 4; ++j) {
        const float p = __expf(sacc[ni][j] - m_run[j]);
        sacc[ni][j] = p;
        psum[j] += p;
      }
#pragma unroll
    for (int d = 1; d < 16; d <<= 1) {
#pragma unroll
      for (int j = 0; j < 4; ++j) psum[j] += __shfl_xor(psum[j], d);
    }
#pragma unroll
    for (int j = 0; j < 4; ++j) l_run[j] = l_run[j] * sc_old[j] + psum[j];
#pragma unroll
    for (int di = 0; di < 4; ++di)
#pragma unroll
      for (int j = 0; j < 4; ++j) yacc[di][j] *= sc_old[j];
    if (hn) scatterV(cur ^ 1, nv0, nv1);
#pragma unroll
    for (int ni = 0; ni < 4; ++ni)
#pragma unroll
      for (int j = 0; j < 4; ++j)
        Ps[w * 1024 + ((fkg << 2) + j) * 64 + ni * 16 + fl] = (h16)sacc[ni][j];
    __syncthreads();
    const half8 pa0 = *reinterpret_cast<const half8*>(&Ps[w * 1024 + fl * 64 + fk]);
    const half8 pa1 = *reinterpret_cast<const half8*>(&Ps[w * 1024 + fl * 64 + 32 + fk]);
#pragma unroll
    for (int di = 0; di < 4; ++di) {
      const half8 vb0 = *reinterpret_cast<const half8*>(&VTs[cur][(di * 16 + fl) * 64 + fk]);
      const half8 vb1 = *reinterpret_cast<const half8*>(&VTs[cur][(di * 16 + fl) * 64 + 32 + fk]);
      yacc[di] = __builtin_amdgcn_mfma_f32_16x16x32_f16(pa0, vb0, yacc[di], 0, 0, 0);
      yacc[di] = __builtin_amdgcn_mfma_f32_16x16x32_f16(pa1, vb1, yacc[di], 0, 0, 0);
    }
    __syncthreads();
    cur ^= 1;
  }
  float rl[4];
#pragma unroll
  for (int j = 0; j < 4; ++j) rl[j] = 1.0f / l_run[j];
  const size_t orow0 = rowQ0 + (fkg << 2);
#pragma unroll
  for (int di = 0; di < 4; ++di)
#pragma unroll
    for (int j = 0; j < 4; ++j)
      yout[(orow0 + j) * E + h * 64 + di * 16 + fl] = (h16)(yacc[di][j] * rl[j]);
}

// ---------------- launch ----------------
extern "C" void kernel_launch(void* const* d_in, const int* in_sizes, int n_in,
                              void* d_out, int out_size, void* d_ws, size_t ws_size,
                              hipStream_t stream) {
  (void)in_sizes; (void)n_in; (void)out_size; (void)ws_size;
  const int* idx = (const int*)d_in[0];
  const float* tok = (const float*)d_in[1];
  const float* pos = (const float*)d_in[2];
  const float* ln1g = (const float*)d_in[3];
  const float* ln1b = (const float*)d_in[4];
  const signed char* attn_qw = (const signed char*)d_in[5];
  const float* attn_s = (const float*)d_in[6];
  const float* attn_b = (const float*)d_in[7];
  const signed char* aproj_qw = (const signed char*)d_in[8];
  const float* aproj_s = (const float*)d_in[9];
  const float* aproj_b = (const float*)d_in[10];
  const float* ln2g = (const float*)d_in[11];
  const float* ln2b = (const float*)d_in[12];
  const signed char* fc_qw = (const signed char*)d_in[13];
  const float* fc_s = (const float*)d_in[14];
  const float* fc_b = (const float*)d_in[15];
  const signed char* mproj_qw = (const signed char*)d_in[16];
  const float* mproj_s = (const float*)d_in[17];
  const float* mproj_b = (const float*)d_in[18];
  const float* lnfg = (const float*)d_in[19];
  const float* lnfb = (const float*)d_in[20];
  const signed char* lm_qw = (const signed char*)d_in[21];
  const float* lm_s = (const float*)d_in[22];

  char* ws = (char*)d_ws;
  size_t off = 0;
  auto alloc = [&](size_t bytes) {
    char* p = ws + off;
    off += (bytes + 255) & ~(size_t)255;
    return p;
  };
  float* x = (float*)alloc((size_t)MROWS * E * 4);     // 8 MB residual
  h16* hbuf = (h16*)alloc((size_t)MROWS * E * 2);      // 4 MB LN out / attn out
  h16* big = (h16*)alloc((size_t)MROWS * 4 * E * 2);   // 16 MB qkv / fc out
  h16* wq = (h16*)alloc((size_t)3 * E2 * 2);
  h16* wa = (h16*)alloc((size_t)E2 * 2);
  h16* wf = (h16*)alloc((size_t)4 * E2 * 2);
  h16* wm = (h16*)alloc((size_t)4 * E2 * 2);
  float* pbuf = (float*)alloc((size_t)4 * MROWS * E * 4);  // 32 MB split-K partials
  h16* wlm = (h16*)alloc((size_t)VOC * E * 2);             // 65.5 MB LM f16 weights
  int* stridew = (int*)alloc(256);
  h16* qkvb = big;
  h16* yb = hbuf;
  h16* hfc = big;

  prep_stride_k<<<1, 256, 0, stream>>>((const unsigned char*)attn_qw,
                                       (const unsigned char*)fc_qw, stridew);
  dequant_all_k<<<VOC * E / 2048, 256, 0, stream>>>(lm_qw, stridew, lm_s, VOC * E,
                                                    wlm, VOC * E);
  embed_k<<<MROWS, 256, 0, stream>>>(idx, tok, pos, x);
  ln_k<<<MROWS, 256, 0, stream>>>(x, ln1g, ln1b, hbuf);  // ln1 for layer 0

  for (int l = 0; l < LAY; ++l) {
    dequant_layer_k<<<12 * E2 / 2048, 256, 0, stream>>>(
        attn_qw, aproj_qw, fc_qw, mproj_qw, attn_s, aproj_s, fc_s, mproj_s, l,
        stridew, wq, wa, wf, wm);
    // qkv: 256x128 tiles -> 8 x 24 = 192 blocks
    gemm_bt<1, 0, 0><<<192, 512, 0, stream>>>(hbuf, wq, attn_b + l * 3 * E, nullptr,
                                              qkvb, MROWS, 3 * E, E, 3 * E);
    attn_k<<<dim3(16, 32), 256, 0, stream>>>(qkvb, yb);
    // aproj: split-K x2, 8 x 8 = 64 blocks per slice
    gemm_btk<<<dim3(64, 2), 512, 0, stream>>>(yb, wa, pbuf, MROWS, E, 512, E);
    reduce_ln_k<<<MROWS, 256, 0, stream>>>(pbuf, 2, aproj_b + l * E, x,
                                           ln2g + l * E, ln2b + l * E, hbuf);
    // fc: 8 x 32 = 256 blocks
    gemm_bt<1, 1, 0><<<256, 512, 0, stream>>>(hbuf, wf, fc_b + l * 4 * E, nullptr,
                                              hfc, MROWS, 4 * E, E, 4 * E);
    // mproj: split-K x4
    gemm_btk<<<dim3(64, 4), 512, 0, stream>>>(hfc, wm, pbuf, MROWS, E, 1024, 4 * E);
    const float* ng = (l < LAY - 1) ? (ln1g + (l + 1) * E) : lnfg;
    const float* nb = (l < LAY - 1) ? (ln1b + (l + 1) * E) : lnfb;
    reduce_ln_k<<<MROWS, 256, 0, stream>>>(pbuf, 4, mproj_b + l * E, x, ng, nb, hbuf);
  }
  // LM head: phase-split counted-vmcnt 256x256 GEMM
  gemm_bt256<<<1000, 512, 0, stream>>>(hbuf, wlm, (float*)d_out, MROWS, VOC, E);
}

// Round 28
// 1735.771 us; speedup vs baseline: 1.0244x; 1.0244x over previous
//
#include <hip/hip_runtime.h>
#include <math.h>

typedef _Float16 h16;
typedef __attribute__((ext_vector_type(8))) _Float16 half8;
typedef __attribute__((ext_vector_type(4))) _Float16 half4;
typedef __attribute__((ext_vector_type(4))) float f32x4;

#define DEVI static __device__ __forceinline__

constexpr int LAY = 8, E = 1024, NH = 16, T = 1024, VOC = 32000, BATCH = 2, HD = 64;
constexpr int MROWS = BATCH * T; // 2048
constexpr int E2 = E * E;

DEVI void glds16(const void* g, void* l) {
  __builtin_amdgcn_global_load_lds((const __attribute__((address_space(1))) void*)g,
                                   (__attribute__((address_space(3))) void*)l, 16, 0, 0);
}

// ---------------- weight-encoding detector (parallel) ----------------
__global__ __launch_bounds__(256) void prep_stride_k(const unsigned char* __restrict__ qw1,
                                                     const unsigned char* __restrict__ qw2,
                                                     int* __restrict__ stridew) {
  __shared__ int red2[4], red4[4];
  const int tid = threadIdx.x;
  const int NB = 8192;
  int c2 = 0, c4 = 0;
  for (int i = tid; i < NB; i += 256) {
    const unsigned char b1 = qw1[i], b2 = qw2[i];
    const int s1 = (b1 == 0x00 || b1 == 0xFF) ? 1 : 0;
    const int s2 = (b2 == 0x00 || b2 == 0xFF) ? 1 : 0;
    if (i & 1) c2 += s1 + s2;
    if (i & 3) c4 += s1 + s2;
  }
#pragma unroll
  for (int d = 32; d >= 1; d >>= 1) { c2 += __shfl_xor(c2, d); c4 += __shfl_xor(c4, d); }
  if ((tid & 63) == 0) { red2[tid >> 6] = c2; red4[tid >> 6] = c4; }
  __syncthreads();
  if (tid == 0) {
    const int t2 = red2[0] + red2[1] + red2[2] + red2[3];
    const int t4 = red4[0] + red4[1] + red4[2] + red4[3];
    int stride = 1;
    if (t4 > (NB * 3 / 2) * 98 / 100) stride = 4;
    else if (t2 > NB * 98 / 100) stride = 2;
    stridew[0] = stride;
  }
}

// ---------------- widened int8 -> 8x f16 loader ----------------
DEVI half8 dq8(const signed char* src, int bstr, float s) {
  half8 o;
  if (bstr == 4) {
    int4 r0 = *reinterpret_cast<const int4*>(src);
    int4 r1 = *reinterpret_cast<const int4*>(src + 16);
    const int* c0 = reinterpret_cast<const int*>(&r0);
    const int* c1 = reinterpret_cast<const int*>(&r1);
#pragma unroll
    for (int j = 0; j < 4; ++j) o[j] = (h16)((float)c0[j] * s);
#pragma unroll
    for (int j = 0; j < 4; ++j) o[4 + j] = (h16)((float)c1[j] * s);
  } else if (bstr == 2) {
    int4 r0 = *reinterpret_cast<const int4*>(src);
    const short* c0 = reinterpret_cast<const short*>(&r0);
#pragma unroll
    for (int j = 0; j < 8; ++j) o[j] = (h16)((float)c0[j] * s);
  } else {
    int2 r0 = *reinterpret_cast<const int2*>(src);
    const signed char* c0 = reinterpret_cast<const signed char*>(&r0);
#pragma unroll
    for (int j = 0; j < 8; ++j) o[j] = (h16)((float)c0[j] * s);
  }
  return o;
}

// ---------------- bulk dequant (single scale region, used for LM) ----------------
__global__ __launch_bounds__(256) void dequant_all_k(const signed char* __restrict__ q,
                                                     const int* __restrict__ strideptr,
                                                     const float* __restrict__ sp, int P,
                                                     h16* __restrict__ out, int n) {
  const int i = (blockIdx.x * 256 + threadIdx.x) * 8;
  if (i >= n) return;
  const float s = sp[i / P];
  const int bstr = strideptr[0];
  *reinterpret_cast<half8*>(out + i) = dq8(q + (size_t)i * (size_t)bstr, bstr, s);
}

// ---------------- merged per-layer dequant: qkv | aproj | fc | mproj ----------------
__global__ __launch_bounds__(256) void dequant_layer_k(
    const signed char* __restrict__ qkv_q, const signed char* __restrict__ ap_q,
    const signed char* __restrict__ fc_q, const signed char* __restrict__ mp_q,
    const float* __restrict__ qkv_s, const float* __restrict__ ap_s,
    const float* __restrict__ fc_s, const float* __restrict__ mp_s, int l,
    const int* __restrict__ strideptr,
    h16* __restrict__ wq, h16* __restrict__ wa, h16* __restrict__ wf,
    h16* __restrict__ wm) {
  const int e = (blockIdx.x * 256 + threadIdx.x) * 8;
  const int bstr = strideptr[0];
  const signed char* src;
  h16* dst;
  float s;
  if (e < 3 * E2) {
    src = qkv_q + ((size_t)l * 3 * E2 + e) * (size_t)bstr;
    dst = wq + e;
    s = qkv_s[l];
  } else if (e < 4 * E2) {
    const int e2 = e - 3 * E2;
    src = ap_q + ((size_t)l * E2 + e2) * (size_t)bstr;
    dst = wa + e2;
    s = ap_s[l];
  } else if (e < 8 * E2) {
    const int e2 = e - 4 * E2;
    src = fc_q + ((size_t)l * 4 * E2 + e2) * (size_t)bstr;
    dst = wf + e2;
    s = fc_s[l];
  } else {
    const int e2 = e - 8 * E2;
    src = mp_q + ((size_t)l * 4 * E2 + e2) * (size_t)bstr;
    dst = wm + e2;
    s = mp_s[l];
  }
  *reinterpret_cast<half8*>(dst) = dq8(src, bstr, s);
}

// ---------------- embedding ----------------
__global__ __launch_bounds__(256) void embed_k(const int* __restrict__ idx,
                                               const float* __restrict__ tok,
                                               const float* __restrict__ pos,
                                               float* __restrict__ x) {
  const int row = blockIdx.x;
  const int t = row & (T - 1);
  const int id = idx[row];
  const float4 a = reinterpret_cast<const float4*>(tok + (size_t)id * E)[threadIdx.x];
  const float4 p = reinterpret_cast<const float4*>(pos + (size_t)t * E)[threadIdx.x];
  float4 o; o.x = a.x + p.x; o.y = a.y + p.y; o.z = a.z + p.z; o.w = a.w + p.w;
  reinterpret_cast<float4*>(x + (size_t)row * E)[threadIdx.x] = o;
}

// ---------------- layernorm (f32 in -> f16 out) ----------------
__global__ __launch_bounds__(256) void ln_k(const float* __restrict__ x,
                                            const float* __restrict__ g,
                                            const float* __restrict__ bb,
                                            h16* __restrict__ out) {
  __shared__ float red[8];
  const int row = blockIdx.x, tid = threadIdx.x;
  const float4 v = reinterpret_cast<const float4*>(x + (size_t)row * E)[tid];
  float s1 = v.x + v.y + v.z + v.w;
  float s2 = v.x * v.x + v.y * v.y + v.z * v.z + v.w * v.w;
#pragma unroll
  for (int d = 32; d >= 1; d >>= 1) { s1 += __shfl_xor(s1, d); s2 += __shfl_xor(s2, d); }
  if ((tid & 63) == 0) { red[tid >> 6] = s1; red[4 + (tid >> 6)] = s2; }
  __syncthreads();
  s1 = red[0] + red[1] + red[2] + red[3];
  s2 = red[4] + red[5] + red[6] + red[7];
  const float mean = s1 * (1.0f / E);
  const float var = s2 * (1.0f / E) - mean * mean;
  const float rstd = rsqrtf(var + 1e-5f);
  const float4 gv = reinterpret_cast<const float4*>(g)[tid];
  const float4 bv = reinterpret_cast<const float4*>(bb)[tid];
  half4 o;
  o[0] = (h16)((v.x - mean) * rstd * gv.x + bv.x);
  o[1] = (h16)((v.y - mean) * rstd * gv.y + bv.y);
  o[2] = (h16)((v.z - mean) * rstd * gv.z + bv.z);
  o[3] = (h16)((v.w - mean) * rstd * gv.w + bv.w);
  *reinterpret_cast<half4*>(out + (size_t)row * E + tid * 4) = o;
}

// ---------------- fused split-K reduce + residual + LN ----------------
__global__ __launch_bounds__(256) void reduce_ln_k(const float* __restrict__ pbuf, int S,
                                                   const float* __restrict__ bias,
                                                   float* __restrict__ x,
                                                   const float* __restrict__ g,
                                                   const float* __restrict__ bb,
                                                   h16* __restrict__ out) {
  __shared__ float red[8];
  const int row = blockIdx.x, tid = threadIdx.x;
  const size_t base = (size_t)row * E + tid * 4;
  float4 a = *reinterpret_cast<const float4*>(pbuf + base);
  for (int s = 1; s < S; ++s) {
    const float4 p = *reinterpret_cast<const float4*>(pbuf + (size_t)s * MROWS * E + base);
    a.x += p.x; a.y += p.y; a.z += p.z; a.w += p.w;
  }
  const float4 bv0 = *reinterpret_cast<const float4*>(bias + tid * 4);
  float4 v = *reinterpret_cast<const float4*>(x + base);
  v.x += a.x + bv0.x; v.y += a.y + bv0.y; v.z += a.z + bv0.z; v.w += a.w + bv0.w;
  *reinterpret_cast<float4*>(x + base) = v;
  float s1 = v.x + v.y + v.z + v.w;
  float s2 = v.x * v.x + v.y * v.y + v.z * v.z + v.w * v.w;
#pragma unroll
  for (int d = 32; d >= 1; d >>= 1) { s1 += __shfl_xor(s1, d); s2 += __shfl_xor(s2, d); }
  if ((tid & 63) == 0) { red[tid >> 6] = s1; red[4 + (tid >> 6)] = s2; }
  __syncthreads();
  s1 = red[0] + red[1] + red[2] + red[3];
  s2 = red[4] + red[5] + red[6] + red[7];
  const float mean = s1 * (1.0f / E);
  const float var = s2 * (1.0f / E) - mean * mean;
  const float rstd = rsqrtf(var + 1e-5f);
  const float4 gv = *reinterpret_cast<const float4*>(g + tid * 4);
  const float4 lb = *reinterpret_cast<const float4*>(bb + tid * 4);
  half4 o;
  o[0] = (h16)((v.x - mean) * rstd * gv.x + lb.x);
  o[1] = (h16)((v.y - mean) * rstd * gv.y + lb.y);
  o[2] = (h16)((v.z - mean) * rstd * gv.z + lb.z);
  o[3] = (h16)((v.w - mean) * rstd * gv.w + lb.w);
  *reinterpret_cast<half4*>(out + (size_t)row * E + tid * 4) = o;
}

// swizzle helper (bit-identical fragment contents, rule #21 both-sides form)
DEVI int swz4(int r) { return (r ^ (r >> 2)) & 3; }

// ---------------- m97 GEMM 128x128: phase-split K-loop, counted vmcnt ----------------
// OUT_KIND: 0 = f32, 1 = f16
template <int OUT_KIND, int DO_GELU, int DO_RESID>
__global__ __launch_bounds__(256) void gemm_bt(const h16* __restrict__ A,
                                               const h16* __restrict__ Bw,
                                               const float* __restrict__ bias,
                                               const float* __restrict__ resid,
                                               void* __restrict__ Cout,
                                               int M, int N, int K, int ldc) {
  __shared__ __align__(16) h16 As[2][4096];
  __shared__ __align__(16) h16 Bs[2][4096];
  const int tid = threadIdx.x;
  const int w = tid >> 6, lane = tid & 63;
  const int lin = blockIdx.x;
  const int cpx = gridDim.x >> 3;
  const int swz = (lin & 7) * cpx + (lin >> 3);
  const int m0 = (swz & 15) << 7;
  const int n0 = (swz >> 4) << 7;
  const int wr = w >> 1, wc = w & 1;
  const int lr = lane >> 2;
  const int lc8 = (((lane & 3) ^ swz4(lr)) << 3);
  const h16* gA = A + (size_t)(m0 + w * 16 + lr) * K + lc8;
  const h16* gB = Bw + (size_t)(n0 + w * 16 + lr) * K + lc8;
  f32x4 acc[4][4] = {};
  const int fl = lane & 15;
  const int fkx = (((lane >> 4) ^ swz4(fl)) << 3);
  const int nk = K >> 5;
  auto stageA = [&](int buf, int kt) {
    const h16* pa = gA + (kt << 5);
    glds16(pa, &As[buf][w * 512]);
    glds16(pa + (size_t)64 * K, &As[buf][2048 + w * 512]);
  };
  auto stageB = [&](int buf, int kt) {
    const h16* pb = gB + (kt << 5);
    glds16(pb, &Bs[buf][w * 512]);
    glds16(pb + (size_t)64 * K, &Bs[buf][2048 + w * 512]);
  };
  stageA(0, 0);
  stageB(0, 0);
  stageB(1, 1);
  asm volatile("s_waitcnt vmcnt(2)" ::: "memory");
  asm volatile("s_barrier" ::: "memory");
  int cur = 0;
  for (int kt = 0; kt < nk; ++kt) {
    half8 af[4], bfr[4];
    // ---- phase 1: mi 0..1 ----
#pragma unroll
    for (int mi = 0; mi < 2; ++mi)
      af[mi] = *reinterpret_cast<const half8*>(&As[cur][(wr * 64 + mi * 16 + fl) * 32 + fkx]);
#pragma unroll
    for (int ni = 0; ni < 4; ++ni)
      bfr[ni] = *reinterpret_cast<const half8*>(&Bs[cur][(wc * 64 + ni * 16 + fl) * 32 + fkx]);
    if (kt + 1 < nk) stageA(cur ^ 1, kt + 1);
    asm volatile("s_waitcnt lgkmcnt(0)" ::: "memory");
    __builtin_amdgcn_sched_barrier(0);
    __builtin_amdgcn_s_setprio(1);
#pragma unroll
    for (int mi = 0; mi < 2; ++mi)
#pragma unroll
      for (int ni = 0; ni < 4; ++ni)
        acc[mi][ni] = __builtin_amdgcn_mfma_f32_16x16x32_f16(af[mi], bfr[ni], acc[mi][ni], 0, 0, 0);
    __builtin_amdgcn_s_setprio(0);
    asm volatile("s_barrier" ::: "memory");
    // ---- phase 2: mi 2..3 ----
#pragma unroll
    for (int mi = 2; mi < 4; ++mi)
      af[mi] = *reinterpret_cast<const half8*>(&As[cur][(wr * 64 + mi * 16 + fl) * 32 + fkx]);
    if (kt + 2 < nk) stageB(cur, kt + 2);
    if (kt < nk - 2)
      asm volatile("s_waitcnt vmcnt(2)" ::: "memory");
    else
      asm volatile("s_waitcnt vmcnt(0)" ::: "memory");
    asm volatile("s_waitcnt lgkmcnt(0)" ::: "memory");
    __builtin_amdgcn_sched_barrier(0);
    __builtin_amdgcn_s_setprio(1);
#pragma unroll
    for (int mi = 2; mi < 4; ++mi)
#pragma unroll
      for (int ni = 0; ni < 4; ++ni)
        acc[mi][ni] = __builtin_amdgcn_mfma_f32_16x16x32_f16(af[mi], bfr[ni], acc[mi][ni], 0, 0, 0);
    __builtin_amdgcn_s_setprio(0);
    asm volatile("s_barrier" ::: "memory");
    cur ^= 1;
  }
  const int fr4 = (lane >> 4) << 2;
#pragma unroll
  for (int mi = 0; mi < 4; ++mi) {
#pragma unroll
    for (int ni = 0; ni < 4; ++ni) {
      const int col = n0 + wc * 64 + ni * 16 + fl;
      const float bv = bias ? bias[col] : 0.0f;
#pragma unroll
      for (int j = 0; j < 4; ++j) {
        const int row = m0 + wr * 64 + mi * 16 + fr4 + j;
        float v = acc[mi][ni][j] + bv;
        if (DO_GELU) v = 0.5f * v * (1.0f + erff(v * 0.70710678118f));
        if (DO_RESID) v += resid[(size_t)row * ldc + col];
        if (OUT_KIND == 1)
          reinterpret_cast<h16*>(Cout)[(size_t)row * ldc + col] = (h16)v;
        else
          reinterpret_cast<float*>(Cout)[(size_t)row * ldc + col] = v;
      }
    }
  }
}

// ---------------- 256x256 8-wave LM GEMM: phase-split, counted vmcnt ------------------
__global__ __launch_bounds__(512) void gemm_bt256(const h16* __restrict__ A,
                                                  const h16* __restrict__ Bw,
                                                  float* __restrict__ Cout,
                                                  int M, int N, int K) {
  __shared__ __align__(16) h16 As[2][8192];
  __shared__ __align__(16) h16 Bs[2][8192];
  const int tid = threadIdx.x;
  const int w = tid >> 6, lane = tid & 63;
  const int lin = blockIdx.x;
  const int cpx = gridDim.x >> 3;
  const int swz = (lin & 7) * cpx + (lin >> 3);
  const int m0 = (swz & 7) << 8;
  const int n0 = (swz >> 3) << 8;
  const int wr = w >> 2, wc = w & 3;  // 2m x 4n waves, wave tile 128x64
  const int lr = lane >> 2;
  const int lc8 = (((lane & 3) ^ swz4(lr)) << 3);
  const h16* gA = A + (size_t)(m0 + w * 16 + lr) * K + lc8;
  const h16* gB = Bw + (size_t)(n0 + w * 16 + lr) * K + lc8;
  f32x4 acc[8][4] = {};
  const int fl = lane & 15;
  const int fkx = (((lane >> 4) ^ swz4(fl)) << 3);
  const int nk = K >> 5;  // 32
  auto stageA = [&](int buf, int kt, int half) {
    glds16(gA + (size_t)(kt << 5) + (size_t)half * 128 * K,
           &As[buf][half * 4096 + w * 512]);
  };
  auto stageB = [&](int buf, int kt, int half) {
    glds16(gB + (size_t)(kt << 5) + (size_t)half * 128 * K,
           &Bs[buf][half * 4096 + w * 512]);
  };
  stageA(0, 0, 0); stageA(0, 0, 1);
  stageB(0, 0, 0); stageB(0, 0, 1);
  stageB(1, 1, 0); stageB(1, 1, 1);
  asm volatile("s_waitcnt vmcnt(2)" ::: "memory");
  asm volatile("s_barrier" ::: "memory");
  int cur = 0;
  for (int kt = 0; kt < nk; ++kt) {
    half8 af[4], bfr[4];
    // ---- phase 1: mlo x n ----
#pragma unroll
    for (int mi = 0; mi < 4; ++mi)
      af[mi] = *reinterpret_cast<const half8*>(&As[cur][(wr * 128 + mi * 16 + fl) * 32 + fkx]);
#pragma unroll
    for (int ni = 0; ni < 4; ++ni)
      bfr[ni] = *reinterpret_cast<const half8*>(&Bs[cur][(wc * 64 + ni * 16 + fl) * 32 + fkx]);
    if (kt + 1 < nk) { stageA(cur ^ 1, kt + 1, 0); stageA(cur ^ 1, kt + 1, 1); }
    asm volatile("s_waitcnt lgkmcnt(0)" ::: "memory");
    __builtin_amdgcn_sched_barrier(0);
    __builtin_amdgcn_s_setprio(1);
#pragma unroll
    for (int mi = 0; mi < 4; ++mi)
#pragma unroll
      for (int ni = 0; ni < 4; ++ni)
        acc[mi][ni] = __builtin_amdgcn_mfma_f32_16x16x32_f16(af[mi], bfr[ni], acc[mi][ni], 0, 0, 0);
    __builtin_amdgcn_s_setprio(0);
    asm volatile("s_barrier" ::: "memory");
    // ---- phase 2: mhi x n ----
#pragma unroll
    for (int mi = 0; mi < 4; ++mi)
      af[mi] = *reinterpret_cast<const half8*>(
          &As[cur][(wr * 128 + 64 + mi * 16 + fl) * 32 + fkx]);
    if (kt + 2 < nk) { stageB(cur, kt + 2, 0); stageB(cur, kt + 2, 1); }
    if (kt < nk - 2)
      asm volatile("s_waitcnt vmcnt(2)" ::: "memory");
    else
      asm volatile("s_waitcnt vmcnt(0)" ::: "memory");
    asm volatile("s_waitcnt lgkmcnt(0)" ::: "memory");
    __builtin_amdgcn_sched_barrier(0);
    __builtin_amdgcn_s_setprio(1);
#pragma unroll
    for (int mi = 0; mi < 4; ++mi)
#pragma unroll
      for (int ni = 0; ni < 4; ++ni)
        acc[4 + mi][ni] =
            __builtin_amdgcn_mfma_f32_16x16x32_f16(af[mi], bfr[ni], acc[4 + mi][ni], 0, 0, 0);
    __builtin_amdgcn_s_setprio(0);
    asm volatile("s_barrier" ::: "memory");
    cur ^= 1;
  }
  const int fr4 = (lane >> 4) << 2;
#pragma unroll
  for (int mi = 0; mi < 8; ++mi)
#pragma unroll
    for (int ni = 0; ni < 4; ++ni) {
      const int col = n0 + wc * 64 + ni * 16 + fl;
#pragma unroll
      for (int j = 0; j < 4; ++j) {
        const int row = m0 + wr * 128 + mi * 16 + fr4 + j;
        Cout[(size_t)row * N + col] = acc[mi][ni][j];
      }
    }
}

// ---------------- split-K GEMM: phase-split, counted vmcnt ----------------
__global__ __launch_bounds__(256) void gemm_btk(const h16* __restrict__ A,
                                                const h16* __restrict__ Bw,
                                                float* __restrict__ pbuf,
                                                int M, int N, int Kc, int ldk) {
  __shared__ __align__(16) h16 As[2][4096];
  __shared__ __align__(16) h16 Bs[2][4096];
  const int tid = threadIdx.x;
  const int w = tid >> 6, lane = tid & 63;
  const int lin = blockIdx.x;
  const int cpx = gridDim.x >> 3;
  const int swz = (lin & 7) * cpx + (lin >> 3);
  const int m0 = (swz & 15) << 7;
  const int n0 = (swz >> 4) << 7;
  const int s = blockIdx.y;
  const int koff = s * Kc;
  const int wr = w >> 1, wc = w & 1;
  const int lr = lane >> 2;
  const int lc8 = (((lane & 3) ^ swz4(lr)) << 3);
  const h16* gA = A + (size_t)(m0 + w * 16 + lr) * ldk + koff + lc8;
  const h16* gB = Bw + (size_t)(n0 + w * 16 + lr) * ldk + koff + lc8;
  f32x4 acc[4][4] = {};
  const int fl = lane & 15;
  const int fkx = (((lane >> 4) ^ swz4(fl)) << 3);
  const int nk = Kc >> 5;
  auto stageA = [&](int buf, int kt) {
    const h16* pa = gA + (kt << 5);
    glds16(pa, &As[buf][w * 512]);
    glds16(pa + (size_t)64 * ldk, &As[buf][2048 + w * 512]);
  };
  auto stageB = [&](int buf, int kt) {
    const h16* pb = gB + (kt << 5);
    glds16(pb, &Bs[buf][w * 512]);
    glds16(pb + (size_t)64 * ldk, &Bs[buf][2048 + w * 512]);
  };
  stageA(0, 0);
  stageB(0, 0);
  stageB(1, 1);
  asm volatile("s_waitcnt vmcnt(2)" ::: "memory");
  asm volatile("s_barrier" ::: "memory");
  int cur = 0;
  for (int kt = 0; kt < nk; ++kt) {
    half8 af[4], bfr[4];
#pragma unroll
    for (int mi = 0; mi < 2; ++mi)
      af[mi] = *reinterpret_cast<const half8*>(&As[cur][(wr * 64 + mi * 16 + fl) * 32 + fkx]);
#pragma unroll
    for (int ni = 0; ni < 4; ++ni)
      bfr[ni] = *reinterpret_cast<const half8*>(&Bs[cur][(wc * 64 + ni * 16 + fl) * 32 + fkx]);
    if (kt + 1 < nk) stageA(cur ^ 1, kt + 1);
    asm volatile("s_waitcnt lgkmcnt(0)" ::: "memory");
    __builtin_amdgcn_sched_barrier(0);
    __builtin_amdgcn_s_setprio(1);
#pragma unroll
    for (int mi = 0; mi < 2; ++mi)
#pragma unroll
      for (int ni = 0; ni < 4; ++ni)
        acc[mi][ni] = __builtin_amdgcn_mfma_f32_16x16x32_f16(af[mi], bfr[ni], acc[mi][ni], 0, 0, 0);
    __builtin_amdgcn_s_setprio(0);
    asm volatile("s_barrier" ::: "memory");
#pragma unroll
    for (int mi = 2; mi < 4; ++mi)
      af[mi] = *reinterpret_cast<const half8*>(&As[cur][(wr * 64 + mi * 16 + fl) * 32 + fkx]);
    if (kt + 2 < nk) stageB(cur, kt + 2);
    if (kt < nk - 2)
      asm volatile("s_waitcnt vmcnt(2)" ::: "memory");
    else
      asm volatile("s_waitcnt vmcnt(0)" ::: "memory");
    asm volatile("s_waitcnt lgkmcnt(0)" ::: "memory");
    __builtin_amdgcn_sched_barrier(0);
    __builtin_amdgcn_s_setprio(1);
#pragma unroll
    for (int mi = 2; mi < 4; ++mi)
#pragma unroll
      for (int ni = 0; ni < 4; ++ni)
        acc[mi][ni] = __builtin_amdgcn_mfma_f32_16x16x32_f16(af[mi], bfr[ni], acc[mi][ni], 0, 0, 0);
    __builtin_amdgcn_s_setprio(0);
    asm volatile("s_barrier" ::: "memory");
    cur ^= 1;
  }
  float* out = pbuf + (size_t)s * M * N;
  const int fr4 = (lane >> 4) << 2;
#pragma unroll
  for (int mi = 0; mi < 4; ++mi)
#pragma unroll
    for (int ni = 0; ni < 4; ++ni) {
      const int col = n0 + wc * 64 + ni * 16 + fl;
#pragma unroll
      for (int j = 0; j < 4; ++j) {
        const int row = m0 + wr * 64 + mi * 16 + fr4 + j;
        out[(size_t)row * N + col] = acc[mi][ni][j];
      }
    }
}

// ---------------- MFMA causal flash attention (dbuf K/V + reversed qt) ----------------
__global__ __launch_bounds__(256) void attn_k(const h16* __restrict__ qkv,
                                              h16* __restrict__ yout) {
  __shared__ __align__(16) h16 Ks[2][4096];
  __shared__ __align__(16) h16 VTs[2][4096];
  __shared__ __align__(16) h16 Ps[4096];
  const int qt = (int)gridDim.x - 1 - (int)blockIdx.x;
  const int bh = blockIdx.y;
  const int b = bh >> 4, h = bh & 15;
  const int tid = threadIdx.x, w = tid >> 6, lane = tid & 63;
  const int fl = lane & 15, fkg = lane >> 4, fk = fkg << 3;
  const size_t rowQ0 = (size_t)b * T + qt * 64 + w * 16;
  const h16* qbase = qkv + (rowQ0 + fl) * 3072 + h * 64;
  const half8 qf0 = *reinterpret_cast<const half8*>(qbase + fk);
  const half8 qf1 = *reinterpret_cast<const half8*>(qbase + 32 + fk);
  f32x4 yacc[4] = {};
  float m_run[4], l_run[4];
#pragma unroll
  for (int j = 0; j < 4; ++j) { m_run[j] = -1e30f; l_run[j] = 0.f; }
  const int q_g0 = qt * 64 + w * 16 + (fkg << 2);
  const int krow = lane >> 3, kcol8 = (lane & 7) << 3;
  const int vrow = tid >> 2, vcol8 = (tid & 3) << 3;

  auto stageK = [&](int kt, int buf) {
    const size_t kbase = (size_t)b * T + kt * 64;
    const h16* gk = qkv + (kbase + w * 8 + krow) * 3072 + E + h * 64 + kcol8;
    glds16(gk, &Ks[buf][w * 512]);
    glds16(gk + (size_t)32 * 3072, &Ks[buf][2048 + w * 512]);
  };
  auto loadV = [&](int kt, int half32) {
    const size_t kbase = (size_t)b * T + kt * 64;
    return *reinterpret_cast<const half8*>(qkv + (kbase + vrow) * 3072 + 2 * E + h * 64 +
                                           vcol8 + half32);
  };
  auto scatterV = [&](int buf, half8 v0, half8 v1) {
#pragma unroll
    for (int e = 0; e < 8; ++e) VTs[buf][(vcol8 + e) * 64 + vrow] = v0[e];
#pragma unroll
    for (int e = 0; e < 8; ++e) VTs[buf][(vcol8 + 32 + e) * 64 + vrow] = v1[e];
  };

  stageK(0, 0);
  {
    half8 v0 = loadV(0, 0), v1 = loadV(0, 32);
    scatterV(0, v0, v1);
  }
  __syncthreads();
  int cur = 0;
  for (int kt = 0; kt <= qt; ++kt) {
    const bool hn = kt < qt;
    half8 nv0, nv1;
    if (hn) {
      stageK(kt + 1, cur ^ 1);
      nv0 = loadV(kt + 1, 0);
      nv1 = loadV(kt + 1, 32);
    }
    f32x4 sacc[4];
#pragma unroll
    for (int ni = 0; ni < 4; ++ni) {
      const half8 kb0 = *reinterpret_cast<const half8*>(&Ks[cur][(ni * 16 + fl) * 64 + fk]);
      const half8 kb1 = *reinterpret_cast<const half8*>(&Ks[cur][(ni * 16 + fl) * 64 + 32 + fk]);
      f32x4 z = {0.f, 0.f, 0.f, 0.f};
      z = __builtin_amdgcn_mfma_f32_16x16x32_f16(qf0, kb0, z, 0, 0, 0);
      z = __builtin_amdgcn_mfma_f32_16x16x32_f16(qf1, kb1, z, 0, 0, 0);
      sacc[ni] = z;
    }
    float tmax[4] = {-1e30f, -1e30f, -1e30f, -1e30f};
#pragma unroll
    for (int ni = 0; ni < 4; ++ni) {
      const int kcol = kt * 64 + ni * 16 + fl;
#pragma unroll
      for (int j = 0; j < 4; ++j) {
        float sv = sacc[ni][j] * 0.125f;
        sv = (kcol > q_g0 + j) ? -1e30f : sv;
        sacc[ni][j] = sv;
        tmax[j] = fmaxf(tmax[j], sv);
      }
    }
#pragma unroll
    for (int d = 1; d < 16; d <<= 1) {
#pragma unroll
      for (int j = 0; j < 4; ++j) tmax[j] = fmaxf(tmax[j], __shfl_xor(tmax[j], d));
    }
    float sc_old[4], psum[4] = {0.f, 0.f, 0.f, 0.f};
#pragma unroll
    for (int j = 0; j < 4; ++j) {
      const float mn = fmaxf(m_run[j], tmax[j]);
      sc_old[j] = __expf(m_run[j] - mn);
      m_run[j] = mn;
    }
#pragma unroll
    for (int ni = 0; ni < 4; ++ni)
#pragma unroll
      for (int j = 0; j < 4; ++j) {
        const float p = __expf(sacc[ni][j] - m_run[j]);
        sacc[ni][j] = p;
        psum[j] += p;
      }
#pragma unroll
    for (int d = 1; d < 16; d <<= 1) {
#pragma unroll
      for (int j = 0; j < 4; ++j) psum[j] += __shfl_xor(psum[j], d);
    }
#pragma unroll
    for (int j = 0; j < 4; ++j) l_run[j] = l_run[j] * sc_old[j] + psum[j];
#pragma unroll
    for (int di = 0; di < 4; ++di)
#pragma unroll
      for (int j = 0; j < 4; ++j) yacc[di][j] *= sc_old[j];
    if (hn) scatterV(cur ^ 1, nv0, nv1);
#pragma unroll
    for (int ni = 0; ni < 4; ++ni)
#pragma unroll
      for (int j = 0; j < 4; ++j)
        Ps[w * 1024 + ((fkg << 2) + j) * 64 + ni * 16 + fl] = (h16)sacc[ni][j];
    __syncthreads();
    const half8 pa0 = *reinterpret_cast<const half8*>(&Ps[w * 1024 + fl * 64 + fk]);
    const half8 pa1 = *reinterpret_cast<const half8*>(&Ps[w * 1024 + fl * 64 + 32 + fk]);
#pragma unroll
    for (int di = 0; di < 4; ++di) {
      const half8 vb0 = *reinterpret_cast<const half8*>(&VTs[cur][(di * 16 + fl) * 64 + fk]);
      const half8 vb1 = *reinterpret_cast<const half8*>(&VTs[cur][(di * 16 + fl) * 64 + 32 + fk]);
      yacc[di] = __builtin_amdgcn_mfma_f32_16x16x32_f16(pa0, vb0, yacc[di], 0, 0, 0);
      yacc[di] = __builtin_amdgcn_mfma_f32_16x16x32_f16(pa1, vb1, yacc[di], 0, 0, 0);
    }
    __syncthreads();
    cur ^= 1;
  }
  float rl[4];
#pragma unroll
  for (int j = 0; j < 4; ++j) rl[j] = 1.0f / l_run[j];
  const size_t orow0 = rowQ0 + (fkg << 2);
#pragma unroll
  for (int di = 0; di < 4; ++di)
#pragma unroll
    for (int j = 0; j < 4; ++j)
      yout[(orow0 + j) * E + h * 64 + di * 16 + fl] = (h16)(yacc[di][j] * rl[j]);
}

// ---------------- launch ----------------
extern "C" void kernel_launch(void* const* d_in, const int* in_sizes, int n_in,
                              void* d_out, int out_size, void* d_ws, size_t ws_size,
                              hipStream_t stream) {
  (void)in_sizes; (void)n_in; (void)out_size; (void)ws_size;
  const int* idx = (const int*)d_in[0];
  const float* tok = (const float*)d_in[1];
  const float* pos = (const float*)d_in[2];
  const float* ln1g = (const float*)d_in[3];
  const float* ln1b = (const float*)d_in[4];
  const signed char* attn_qw = (const signed char*)d_in[5];
  const float* attn_s = (const float*)d_in[6];
  const float* attn_b = (const float*)d_in[7];
  const signed char* aproj_qw = (const signed char*)d_in[8];
  const float* aproj_s = (const float*)d_in[9];
  const float* aproj_b = (const float*)d_in[10];
  const float* ln2g = (const float*)d_in[11];
  const float* ln2b = (const float*)d_in[12];
  const signed char* fc_qw = (const signed char*)d_in[13];
  const float* fc_s = (const float*)d_in[14];
  const float* fc_b = (const float*)d_in[15];
  const signed char* mproj_qw = (const signed char*)d_in[16];
  const float* mproj_s = (const float*)d_in[17];
  const float* mproj_b = (const float*)d_in[18];
  const float* lnfg = (const float*)d_in[19];
  const float* lnfb = (const float*)d_in[20];
  const signed char* lm_qw = (const signed char*)d_in[21];
  const float* lm_s = (const float*)d_in[22];

  char* ws = (char*)d_ws;
  size_t off = 0;
  auto alloc = [&](size_t bytes) {
    char* p = ws + off;
    off += (bytes + 255) & ~(size_t)255;
    return p;
  };
  float* x = (float*)alloc((size_t)MROWS * E * 4);     // 8 MB residual
  h16* hbuf = (h16*)alloc((size_t)MROWS * E * 2);      // 4 MB LN out / attn out
  h16* big = (h16*)alloc((size_t)MROWS * 4 * E * 2);   // 16 MB qkv / fc out
  h16* wq = (h16*)alloc((size_t)3 * E2 * 2);
  h16* wa = (h16*)alloc((size_t)E2 * 2);
  h16* wf = (h16*)alloc((size_t)4 * E2 * 2);
  h16* wm = (h16*)alloc((size_t)4 * E2 * 2);
  float* pbuf = (float*)alloc((size_t)4 * MROWS * E * 4);  // 32 MB split-K partials
  h16* wlm = (h16*)alloc((size_t)VOC * E * 2);             // 65.5 MB LM f16 weights
  int* stridew = (int*)alloc(256);
  h16* qkvb = big;
  h16* yb = hbuf;
  h16* hfc = big;

  prep_stride_k<<<1, 256, 0, stream>>>((const unsigned char*)attn_qw,
                                       (const unsigned char*)fc_qw, stridew);
  dequant_all_k<<<VOC * E / 2048, 256, 0, stream>>>(lm_qw, stridew, lm_s, VOC * E,
                                                    wlm, VOC * E);
  embed_k<<<MROWS, 256, 0, stream>>>(idx, tok, pos, x);
  ln_k<<<MROWS, 256, 0, stream>>>(x, ln1g, ln1b, hbuf);  // ln1 for layer 0

  for (int l = 0; l < LAY; ++l) {
    dequant_layer_k<<<12 * E2 / 2048, 256, 0, stream>>>(
        attn_qw, aproj_qw, fc_qw, mproj_qw, attn_s, aproj_s, fc_s, mproj_s, l,
        stridew, wq, wa, wf, wm);
    gemm_bt<1, 0, 0><<<24 * 16, 256, 0, stream>>>(hbuf, wq, attn_b + l * 3 * E, nullptr,
                                                  qkvb, MROWS, 3 * E, E, 3 * E);
    attn_k<<<dim3(16, 32), 256, 0, stream>>>(qkvb, yb);
    gemm_btk<<<dim3(128, 2), 256, 0, stream>>>(yb, wa, pbuf, MROWS, E, 512, E);
    reduce_ln_k<<<MROWS, 256, 0, stream>>>(pbuf, 2, aproj_b + l * E, x,
                                           ln2g + l * E, ln2b + l * E, hbuf);
    gemm_bt<1, 1, 0><<<32 * 16, 256, 0, stream>>>(hbuf, wf, fc_b + l * 4 * E, nullptr,
                                                  hfc, MROWS, 4 * E, E, 4 * E);
    gemm_btk<<<dim3(128, 4), 256, 0, stream>>>(hfc, wm, pbuf, MROWS, E, 1024, 4 * E);
    const float* ng = (l < LAY - 1) ? (ln1g + (l + 1) * E) : lnfg;
    const float* nb = (l < LAY - 1) ? (ln1b + (l + 1) * E) : lnfb;
    reduce_ln_k<<<MROWS, 256, 0, stream>>>(pbuf, 4, mproj_b + l * E, x, ng, nb, hbuf);
  }
  // LM head: phase-split counted-vmcnt 256x256 GEMM
  gemm_bt256<<<1000, 512, 0, stream>>>(hbuf, wlm, (float*)d_out, MROWS, VOC, E);
}